// Round 3
// baseline (2317.208 us; speedup 1.0000x reference)
//
#include <hip/hip_runtime.h>
#include <hip/hip_bf16.h>
#include <math.h>

#define DMODEL 2048
#define SEQ    2048
#define BATCH  2
#define NH     32
#define NG     8
#define DH     64

typedef unsigned short ushort_t;

__device__ __forceinline__ float bf2f(unsigned short u) {
    unsigned int x = ((unsigned int)u) << 16;
    return __uint_as_float(x);
}
__device__ __forceinline__ unsigned short f2bf(float f) {
    unsigned int x = __float_as_uint(f);
    unsigned int r = (x + 0x7fffu + ((x >> 16) & 1u)) >> 16;
    return (unsigned short)r;
}

#define NEG_BIG (-1.0e30f)

// Canonical bf16 workspace layout (element offsets)
#define C_HS   0u
#define C_WQ   8388608u
#define C_WK   12582912u
#define C_WV   13631488u
#define C_WO   14680064u
#define C_BO   18874368u
#define C_END  18876416u
#define W_Q    18876416u
#define W_K    27265024u
#define W_V    29362176u
#define W_CTX  31459328u

// ---------------------------------------------------------------------------
// Runtime input-dtype detection. Interpret first 2048 ushorts of
// hidden_states as bf16; data is N(0,1) so max|x|~4 if storage is bf16.
// If storage is fp32, half those ushorts are raw mantissa bits (uniform
// exponent byte) -> max blows past 1e6 with certainty. Deterministic,
// graph-safe, recomputed independently per block (no cross-block comm).
// Requires blockDim.x == 256; `red` is 4 floats of LDS scratch.
// ---------------------------------------------------------------------------
__device__ __forceinline__ bool detect_is_f32(const ushort_t* hsu, int tid, float* red)
{
    ushort4 a = *(const ushort4*)(hsu + tid * 8);
    ushort4 b = *(const ushort4*)(hsu + tid * 8 + 4);
    ushort_t vals[8] = {a.x, a.y, a.z, a.w, b.x, b.y, b.z, b.w};
    float mymax = 0.0f;
    #pragma unroll
    for (int e = 0; e < 8; ++e) {
        float v = bf2f(vals[e]);
        float av = fabsf(v);
        if (!(av < 1.0e30f)) av = 1.0e30f;   // NaN/inf -> huge finite
        mymax = fmaxf(mymax, av);
    }
    #pragma unroll
    for (int off = 1; off < 64; off <<= 1)
        mymax = fmaxf(mymax, __shfl_xor(mymax, off, 64));
    if ((tid & 63) == 0) red[tid >> 6] = mymax;
    __syncthreads();
    float m = fmaxf(fmaxf(red[0], red[1]), fmaxf(red[2], red[3]));
    __syncthreads();   // protect red before caller reuses the LDS
    return m > 1.0e6f;
}

// ---------------------------------------------------------------------------
// Kernel 0: convert all 6 inputs to canonical bf16 in ws.
// Concatenated element space: hs | Wq | Wk | Wv | Wo | bo = 18,876,416 elems.
// 2048 elems per block -> 9217 blocks exactly. Region sizes are multiples of
// 2048 so no chunk crosses a boundary.
// ---------------------------------------------------------------------------
__global__ __launch_bounds__(256)
void convert_inputs_kernel(const void* __restrict__ hs, const void* __restrict__ Wq,
                           const void* __restrict__ Wk, const void* __restrict__ Wv,
                           const void* __restrict__ Wo, const void* __restrict__ bo,
                           ushort_t* __restrict__ canon)
{
    __shared__ float red[4];
    const int tid = threadIdx.x;
    const bool is_f32 = detect_is_f32((const ushort_t*)hs, tid, red);

    unsigned int g = (blockIdx.x * 256u + tid) * 8u;
    const void* src; unsigned int loc;
    if (g < C_WQ)      { src = hs; loc = g; }
    else if (g < C_WK) { src = Wq; loc = g - C_WQ; }
    else if (g < C_WV) { src = Wk; loc = g - C_WK; }
    else if (g < C_WO) { src = Wv; loc = g - C_WV; }
    else if (g < C_BO) { src = Wo; loc = g - C_WO; }
    else               { src = bo; loc = g - C_BO; }

    ushort4 o0, o1;
    if (is_f32) {
        const float* f = (const float*)src + loc;
        float4 x = *(const float4*)f;
        float4 y = *(const float4*)(f + 4);
        o0.x = f2bf(x.x); o0.y = f2bf(x.y); o0.z = f2bf(x.z); o0.w = f2bf(x.w);
        o1.x = f2bf(y.x); o1.y = f2bf(y.y); o1.z = f2bf(y.z); o1.w = f2bf(y.w);
    } else {
        const ushort_t* u = (const ushort_t*)src + loc;
        o0 = *(const ushort4*)u;
        o1 = *(const ushort4*)(u + 4);
    }
    *(ushort4*)(canon + g)     = o0;
    *(ushort4*)(canon + g + 4) = o1;
}

// ---------------------------------------------------------------------------
// Kernel 1: QKV projection + interleaved RoPE (all-bf16 canon inputs).
// ---------------------------------------------------------------------------
__global__ __launch_bounds__(256)
void qkv_rope_kernel(const ushort_t* __restrict__ hs,
                     const ushort_t* __restrict__ Wq,
                     const ushort_t* __restrict__ Wk,
                     const ushort_t* __restrict__ Wv,
                     ushort_t* __restrict__ qws, ushort_t* __restrict__ kws,
                     ushort_t* __restrict__ vws)
{
    __shared__ __align__(16) float As[32][68];   // [k][m]
    __shared__ __align__(16) float Ws[32][68];   // [k][n]
    const int tid = threadIdx.x;
    const int i = tid >> 4, j = tid & 15;
    const int row0 = blockIdx.x * 64;
    const int n0   = blockIdx.y * 64;

    const ushort_t* Wb; int ldw, nb;
    if (n0 < 2048)      { Wb = Wq; ldw = 2048; nb = n0; }
    else if (n0 < 2560) { Wb = Wk; ldw = 512;  nb = n0 - 2048; }
    else                { Wb = Wv; ldw = 512;  nb = n0 - 2560; }

    float acc[4][4] = {};

    for (int k0 = 0; k0 < DMODEL; k0 += 32) {
        #pragma unroll
        for (int t = 0; t < 2; ++t) {
            int idx = tid + t * 256;
            int r  = idx >> 3;
            int kq = (idx & 7) << 2;
            ushort4 u = *(const ushort4*)(hs + (size_t)(row0 + r) * DMODEL + k0 + kq);
            As[kq+0][r] = bf2f(u.x); As[kq+1][r] = bf2f(u.y);
            As[kq+2][r] = bf2f(u.z); As[kq+3][r] = bf2f(u.w);
        }
        #pragma unroll
        for (int t = 0; t < 2; ++t) {
            int idx = tid + t * 256;
            int kk = idx >> 4;
            int nq = (idx & 15) << 2;
            ushort4 u = *(const ushort4*)(Wb + (size_t)(k0 + kk) * ldw + nb + nq);
            float4 w4 = make_float4(bf2f(u.x), bf2f(u.y), bf2f(u.z), bf2f(u.w));
            *(float4*)&Ws[kk][nq] = w4;
        }
        __syncthreads();
        #pragma unroll 8
        for (int kk = 0; kk < 32; ++kk) {
            float4 a4 = *(const float4*)&As[kk][4*i];
            float4 w4 = *(const float4*)&Ws[kk][4*j];
            float a[4] = {a4.x, a4.y, a4.z, a4.w};
            float w[4] = {w4.x, w4.y, w4.z, w4.w};
            #pragma unroll
            for (int r = 0; r < 4; ++r)
                #pragma unroll
                for (int c = 0; c < 4; ++c)
                    acc[r][c] += a[r] * w[c];
        }
        __syncthreads();
    }

    const float LOG1E4_64 = 0.14391156509880297f; // ln(10000)/64
    const int col = n0 + 4*j;
    #pragma unroll
    for (int r = 0; r < 4; ++r) {
        int grow = row0 + 4*i + r;
        int b = grow >> 11, s = grow & (SEQ - 1);
        if (col < 2560) {  // Q or K: interleaved RoPE; precise sincos (|x|<=2047 rad)
            int d0 = col & 63;
            #pragma unroll
            for (int p = 0; p < 4; p += 2) {
                float freq = expf(-(float)(d0 + p) * LOG1E4_64);
                float ang = (float)s * freq;
                float sn, cs;
                sincosf(ang, &sn, &cs);
                float x0 = acc[r][p], x1 = acc[r][p+1];
                acc[r][p]   = x0 * cs - x1 * sn;
                acc[r][p+1] = x1 * cs + x0 * sn;
            }
        }
        ushort4 u;
        u.x = f2bf(acc[r][0]); u.y = f2bf(acc[r][1]);
        u.z = f2bf(acc[r][2]); u.w = f2bf(acc[r][3]);
        if (col < 2048) {
            int h = col >> 6, d0 = col & 63;
            *(ushort4*)&qws[((size_t)(b*NH + h) * SEQ + s) * DH + d0] = u;
        } else if (col < 2560) {
            int g = (col - 2048) >> 6, d0 = col & 63;
            *(ushort4*)&kws[((size_t)(b*NG + g) * SEQ + s) * DH + d0] = u;
        } else {
            int g = (col - 2560) >> 6, d0 = col & 63;
            *(ushort4*)&vws[((size_t)(b*NG + g) * SEQ + s) * DH + d0] = u;
        }
    }
}

// ---------------------------------------------------------------------------
// Kernel 2: flash-style causal attention with ALiBi + 30*tanh(s/30).
// ---------------------------------------------------------------------------
__global__ __launch_bounds__(256)
void attn_kernel(const ushort_t* __restrict__ qws, const ushort_t* __restrict__ kws,
                 const ushort_t* __restrict__ vws, ushort_t* __restrict__ ctx)
{
    __shared__ __align__(16) float Qt[64][68];   // [d][qrow]
    __shared__ __align__(16) float Kt[64][68];   // [d][kcol]
    __shared__ __align__(16) float Vs[64][68];   // [kpos][d]
    __shared__ __align__(16) float Pt[64][68];   // [kpos][qrow]

    const int tid = threadIdx.x;
    const int i = tid >> 4, j = tid & 15;
    const int qt = blockIdx.x;
    const int h  = blockIdx.y;
    const int b  = blockIdx.z;
    const int g  = h >> 2;
    const int q0 = qt * 64;

    const float slope = exp2f(-0.25f * (float)(h + 1));
    const ushort_t* qbase = qws + (size_t)(b*NH + h) * SEQ * DH;
    const ushort_t* kbase = kws + (size_t)(b*NG + g) * SEQ * DH;
    const ushort_t* vbase = vws + (size_t)(b*NG + g) * SEQ * DH;

    #pragma unroll
    for (int t = 0; t < 4; ++t) {
        int e = tid + t * 256;
        int r  = e >> 4;
        int d4 = (e & 15) << 2;
        ushort4 u = *(const ushort4*)&qbase[(size_t)(q0 + r) * DH + d4];
        Qt[d4+0][r] = bf2f(u.x); Qt[d4+1][r] = bf2f(u.y);
        Qt[d4+2][r] = bf2f(u.z); Qt[d4+3][r] = bf2f(u.w);
    }

    float o[4][4] = {};
    float mrow[4] = {NEG_BIG, NEG_BIG, NEG_BIG, NEG_BIG};
    float lrow[4] = {};

    for (int kt = 0; kt <= qt; ++kt) {
        const int k0 = kt * 64;
        __syncthreads();
        #pragma unroll
        for (int t = 0; t < 4; ++t) {
            int e = tid + t * 256;
            int r  = e >> 4;
            int d4 = (e & 15) << 2;
            ushort4 ku = *(const ushort4*)&kbase[(size_t)(k0 + r) * DH + d4];
            Kt[d4+0][r] = bf2f(ku.x); Kt[d4+1][r] = bf2f(ku.y);
            Kt[d4+2][r] = bf2f(ku.z); Kt[d4+3][r] = bf2f(ku.w);
            ushort4 vu = *(const ushort4*)&vbase[(size_t)(k0 + r) * DH + d4];
            float4 vv = make_float4(bf2f(vu.x), bf2f(vu.y), bf2f(vu.z), bf2f(vu.w));
            *(float4*)&Vs[r][d4] = vv;
        }
        __syncthreads();

        float sc[4][4] = {};
        #pragma unroll 8
        for (int kk = 0; kk < 64; ++kk) {
            float4 a4 = *(const float4*)&Qt[kk][4*i];
            float4 b4 = *(const float4*)&Kt[kk][4*j];
            float a[4] = {a4.x, a4.y, a4.z, a4.w};
            float bb[4] = {b4.x, b4.y, b4.z, b4.w};
            #pragma unroll
            for (int r = 0; r < 4; ++r)
                #pragma unroll
                for (int c = 0; c < 4; ++c)
                    sc[r][c] += a[r] * bb[c];
        }

        #pragma unroll
        for (int r = 0; r < 4; ++r) {
            int qpos = q0 + 4*i + r;
            #pragma unroll
            for (int c = 0; c < 4; ++c) {
                int kpos = k0 + 4*j + c;
                float sv = (sc[r][c] - fabsf((float)(qpos - kpos)) * slope) * 0.125f;
                float x = sv * (1.0f / 30.0f);
                float ax = fabsf(x);
                float t = __expf(-2.0f * ax);
                float th = (1.0f - t) / (1.0f + t);
                sv = 30.0f * ((x >= 0.0f) ? th : -th);
                if (kpos > qpos) sv = NEG_BIG;
                sc[r][c] = sv;
            }
        }

        #pragma unroll
        for (int r = 0; r < 4; ++r) {
            float mx = fmaxf(fmaxf(sc[r][0], sc[r][1]), fmaxf(sc[r][2], sc[r][3]));
            #pragma unroll
            for (int off = 1; off < 16; off <<= 1)
                mx = fmaxf(mx, __shfl_xor(mx, off, 64));
            float mnew = fmaxf(mrow[r], mx);
            float alpha = __expf(mrow[r] - mnew);
            float psum = 0.0f;
            #pragma unroll
            for (int c = 0; c < 4; ++c) {
                float p = __expf(sc[r][c] - mnew);
                sc[r][c] = p;
                psum += p;
            }
            #pragma unroll
            for (int off = 1; off < 16; off <<= 1)
                psum += __shfl_xor(psum, off, 64);
            lrow[r] = lrow[r] * alpha + psum;
            mrow[r] = mnew;
            #pragma unroll
            for (int c = 0; c < 4; ++c) o[r][c] *= alpha;
        }

        #pragma unroll
        for (int r = 0; r < 4; ++r)
            #pragma unroll
            for (int c = 0; c < 4; ++c)
                Pt[4*j+c][4*i+r] = sc[r][c];
        __syncthreads();

        #pragma unroll 8
        for (int kk = 0; kk < 64; ++kk) {
            float4 p4 = *(const float4*)&Pt[kk][4*i];
            float4 v4 = *(const float4*)&Vs[kk][4*j];
            float p[4] = {p4.x, p4.y, p4.z, p4.w};
            float vv[4] = {v4.x, v4.y, v4.z, v4.w};
            #pragma unroll
            for (int r = 0; r < 4; ++r)
                #pragma unroll
                for (int c = 0; c < 4; ++c)
                    o[r][c] += p[r] * vv[c];
        }
    }

    #pragma unroll
    for (int r = 0; r < 4; ++r) {
        int s = q0 + 4*i + r;
        float inv = 1.0f / lrow[r];
        ushort4 u;
        u.x = f2bf(o[r][0]*inv); u.y = f2bf(o[r][1]*inv);
        u.z = f2bf(o[r][2]*inv); u.w = f2bf(o[r][3]*inv);
        *(ushort4*)&ctx[((size_t)(b*SEQ + s) * NH + h) * DH + 4*j] = u;
    }
}

// ---------------------------------------------------------------------------
// Kernel 3: out = ctx @ Wo + bo. Writes d_out as bf16 or fp32 per detected
// input flavor (harness converts all-or-none).
// ---------------------------------------------------------------------------
__global__ __launch_bounds__(256)
void oproj_kernel(const ushort_t* __restrict__ ctx,
                  const ushort_t* __restrict__ Wo,
                  const ushort_t* __restrict__ bo,
                  const ushort_t* __restrict__ hs_orig,
                  void* __restrict__ outp)
{
    __shared__ __align__(16) float As[32][68];   // [k][m]  (first 4 floats double as detect scratch)
    __shared__ __align__(16) float Ws[32][68];   // [k][n]
    const int tid = threadIdx.x;
    const bool is_f32 = detect_is_f32(hs_orig, tid, &As[0][0]);
    const int i = tid >> 4, j = tid & 15;
    const int row0 = blockIdx.x * 64;
    const int n0   = blockIdx.y * 64;

    float acc[4][4] = {};

    for (int k0 = 0; k0 < DMODEL; k0 += 32) {
        #pragma unroll
        for (int t = 0; t < 2; ++t) {
            int idx = tid + t * 256;
            int r  = idx >> 3;
            int kq = (idx & 7) << 2;
            ushort4 u = *(const ushort4*)(ctx + (size_t)(row0 + r) * DMODEL + k0 + kq);
            As[kq+0][r] = bf2f(u.x); As[kq+1][r] = bf2f(u.y);
            As[kq+2][r] = bf2f(u.z); As[kq+3][r] = bf2f(u.w);
        }
        #pragma unroll
        for (int t = 0; t < 2; ++t) {
            int idx = tid + t * 256;
            int kk = idx >> 4;
            int nq = (idx & 15) << 2;
            ushort4 u = *(const ushort4*)(Wo + (size_t)(k0 + kk) * DMODEL + n0 + nq);
            float4 w4 = make_float4(bf2f(u.x), bf2f(u.y), bf2f(u.z), bf2f(u.w));
            *(float4*)&Ws[kk][nq] = w4;
        }
        __syncthreads();
        #pragma unroll 8
        for (int kk = 0; kk < 32; ++kk) {
            float4 a4 = *(const float4*)&As[kk][4*i];
            float4 w4 = *(const float4*)&Ws[kk][4*j];
            float a[4] = {a4.x, a4.y, a4.z, a4.w};
            float w[4] = {w4.x, w4.y, w4.z, w4.w};
            #pragma unroll
            for (int r = 0; r < 4; ++r)
                #pragma unroll
                for (int c = 0; c < 4; ++c)
                    acc[r][c] += a[r] * w[c];
        }
        __syncthreads();
    }

    const int n = n0 + 4*j;
    ushort4 b4 = *(const ushort4*)(bo + n);
    float bias[4] = {bf2f(b4.x), bf2f(b4.y), bf2f(b4.z), bf2f(b4.w)};
    #pragma unroll
    for (int r = 0; r < 4; ++r) {
        int grow = row0 + 4*i + r;
        float v0 = acc[r][0] + bias[0], v1 = acc[r][1] + bias[1];
        float v2 = acc[r][2] + bias[2], v3 = acc[r][3] + bias[3];
        if (is_f32) {
            float* of = (float*)outp;
            *(float4*)&of[(size_t)grow * DMODEL + n] = make_float4(v0, v1, v2, v3);
        } else {
            ushort_t* ob = (ushort_t*)outp;
            ushort4 u;
            u.x = f2bf(v0); u.y = f2bf(v1); u.z = f2bf(v2); u.w = f2bf(v3);
            *(ushort4*)&ob[(size_t)grow * DMODEL + n] = u;
        }
    }
}

extern "C" void kernel_launch(void* const* d_in, const int* in_sizes, int n_in,
                              void* d_out, int out_size, void* d_ws, size_t ws_size,
                              hipStream_t stream) {
    ushort_t* ws = (ushort_t*)d_ws;
    ushort_t* canon = ws;
    ushort_t* qws = ws + W_Q;
    ushort_t* kws = ws + W_K;
    ushort_t* vws = ws + W_V;
    ushort_t* ctx = ws + W_CTX;   // end: 39,847,936 elems = 76 MB

    convert_inputs_kernel<<<dim3(9217), 256, 0, stream>>>(
        d_in[0], d_in[1], d_in[2], d_in[3], d_in[4], d_in[5], canon);
    qkv_rope_kernel<<<dim3(64, 48), 256, 0, stream>>>(
        canon + C_HS, canon + C_WQ, canon + C_WK, canon + C_WV, qws, kws, vws);
    attn_kernel<<<dim3(SEQ/64, NH, BATCH), 256, 0, stream>>>(qws, kws, vws, ctx);
    oproj_kernel<<<dim3(64, 32), 256, 0, stream>>>(
        ctx, canon + C_WO, canon + C_BO, (const ushort_t*)d_in[0], d_out);
}

// Round 5
// 732.264 us; speedup vs baseline: 3.1644x; 3.1644x over previous
//
#include <hip/hip_runtime.h>
#include <hip/hip_bf16.h>
#include <math.h>

#define DMODEL 2048
#define SEQ    2048
#define NH     32
#define NG     8
#define DH     64

typedef unsigned short u16;
using v8bf  = __attribute__((ext_vector_type(8))) __bf16;
using f32x4 = __attribute__((ext_vector_type(4))) float;

__device__ __forceinline__ float bf2f(u16 u) {
    unsigned int x = ((unsigned int)u) << 16;
    return __uint_as_float(x);
}
__device__ __forceinline__ u16 f2bf(float f) {
    unsigned int x = __float_as_uint(f);
    unsigned int r = (x + 0x7fffu + ((x >> 16) & 1u)) >> 16;
    return (u16)r;
}
__device__ __forceinline__ f32x4 mfma16(v8bf a, v8bf b, f32x4 c) {
    return __builtin_amdgcn_mfma_f32_16x16x32_bf16(a, b, c, 0, 0, 0);
}

#define NEG_BIG (-1.0e30f)
#define LOG1E4_64 0.14391156509880297f

// Canonical ws layout (u16 element offsets). Weights stored TRANSPOSED [n][k].
// RoPE float table OVERLAPS the ctx region (W_ROPE == W_CTX): it is written
// by rope_table, consumed by gemm_qkv, and only THEN does attn overwrite the
// region with ctx — safe by stream order within every launch/replay, and
// keeps total ws footprint at the R3-proven 79,695,872 bytes.
#define C_HS   0u
#define C_WQ   8388608u
#define C_WK   12582912u
#define C_WV   13631488u
#define C_WO   14680064u
#define C_BO   18874368u
#define W_Q    18876416u   // [b,h][s][d]
#define W_K    27265024u   // [b,g][s][d]
#define W_V    29362176u   // [b,g][d][s]  (transposed for PV B-operand)
#define W_CTX  31459328u   // [b,s][h*64+d]  (also hosts the transient RoPE table)

// ---------------------------------------------------------------------------
// Runtime input-dtype detection (R3-verified). bf16-interpret first 2048
// ushorts of hidden_states: N(0,1) bf16 -> max ~4; raw fp32 bits -> >1e6.
// ---------------------------------------------------------------------------
__device__ __forceinline__ bool detect_is_f32(const u16* hsu, int tid, float* red)
{
    ushort4 a = *(const ushort4*)(hsu + tid * 8);
    ushort4 b = *(const ushort4*)(hsu + tid * 8 + 4);
    u16 vals[8] = {a.x, a.y, a.z, a.w, b.x, b.y, b.z, b.w};
    float mymax = 0.0f;
    #pragma unroll
    for (int e = 0; e < 8; ++e) {
        float av = fabsf(bf2f(vals[e]));
        if (!(av < 1.0e30f)) av = 1.0e30f;
        mymax = fmaxf(mymax, av);
    }
    #pragma unroll
    for (int off = 1; off < 64; off <<= 1)
        mymax = fmaxf(mymax, __shfl_xor(mymax, off, 64));
    if ((tid & 63) == 0) red[tid >> 6] = mymax;
    __syncthreads();
    float m = fmaxf(fmaxf(red[0], red[1]), fmaxf(red[2], red[3]));
    __syncthreads();
    return m > 1.0e6f;
}

// ---------------------------------------------------------------------------
// Prelude A: convert hs + bo to canonical bf16 (straight copy/round).
// ---------------------------------------------------------------------------
__global__ __launch_bounds__(256)
void conv_hs_bo(const void* __restrict__ hs, const void* __restrict__ bo,
                u16* __restrict__ canon)
{
    __shared__ float red[4];
    const int tid = threadIdx.x;
    const bool is_f32 = detect_is_f32((const u16*)hs, tid, red);
    unsigned int g = (blockIdx.x * 256u + tid) * 8u;
    const void* src; unsigned int loc; u16* dst;
    if (g < 8388608u) { src = hs; loc = g;            dst = canon + C_HS + g; }
    else              { src = bo; loc = g - 8388608u; dst = canon + C_BO + loc; }

    ushort4 o0, o1;
    if (is_f32) {
        const float* f = (const float*)src + loc;
        float4 x = *(const float4*)f;
        float4 y = *(const float4*)(f + 4);
        o0.x = f2bf(x.x); o0.y = f2bf(x.y); o0.z = f2bf(x.z); o0.w = f2bf(x.w);
        o1.x = f2bf(y.x); o1.y = f2bf(y.y); o1.z = f2bf(y.z); o1.w = f2bf(y.w);
    } else {
        const u16* u = (const u16*)src + loc;
        o0 = *(const ushort4*)u;
        o1 = *(const ushort4*)(u + 4);
    }
    *(ushort4*)dst       = o0;
    *(ushort4*)(dst + 4) = o1;
}

// ---------------------------------------------------------------------------
// Prelude B: tiled transpose-convert of a weight matrix (K x N) -> bf16 [n][k].
// ---------------------------------------------------------------------------
__global__ __launch_bounds__(256)
void transp_w(const void* __restrict__ W, u16* __restrict__ dst,
              int K, int N, const u16* __restrict__ hs_orig)
{
    __shared__ float red[4];
    __shared__ u16 Ts[64][68];
    const int tid = threadIdx.x;
    const bool is_f32 = detect_is_f32(hs_orig, tid, red);
    const int n0 = blockIdx.x * 64, k0 = blockIdx.y * 64;

    #pragma unroll
    for (int it = 0; it < 4; ++it) {
        int e  = tid + it * 256;
        int kr = e >> 4, n4 = (e & 15) << 2;
        if (is_f32) {
            const float* s = (const float*)W + (size_t)(k0 + kr) * N + n0 + n4;
            float4 x = *(const float4*)s;
            Ts[n4+0][kr] = f2bf(x.x); Ts[n4+1][kr] = f2bf(x.y);
            Ts[n4+2][kr] = f2bf(x.z); Ts[n4+3][kr] = f2bf(x.w);
        } else {
            ushort4 u = *(const ushort4*)((const u16*)W + (size_t)(k0 + kr) * N + n0 + n4);
            Ts[n4+0][kr] = u.x; Ts[n4+1][kr] = u.y;
            Ts[n4+2][kr] = u.z; Ts[n4+3][kr] = u.w;
        }
    }
    __syncthreads();
    #pragma unroll
    for (int it = 0; it < 4; ++it) {
        int e  = tid + it * 256;
        int nr = e >> 4, k4 = (e & 15) << 2;
        ushort4 u;
        u.x = Ts[nr][k4+0]; u.y = Ts[nr][k4+1];
        u.z = Ts[nr][k4+2]; u.w = Ts[nr][k4+3];
        *(ushort4*)(dst + (size_t)(n0 + nr) * K + k0 + k4) = u;
    }
}

// ---------------------------------------------------------------------------
// Prelude C: RoPE table. cos/sin[s][d] = cos/sin(s * 10000^(-(d&~1)/64)).
// Precise sincosf (angles to 2047 rad — outside native v_sin domain).
// ---------------------------------------------------------------------------
__global__ __launch_bounds__(256)
void rope_table(float* __restrict__ c, float* __restrict__ s)
{
    int idx = blockIdx.x * 256 + threadIdx.x;     // 131072 total
    int sq = idx >> 6, d = idx & 63;
    float freq = expf(-(float)(d & ~1) * LOG1E4_64);
    float sn, cs;
    sincosf((float)sq * freq, &sn, &cs);
    c[idx] = cs; s[idx] = sn;
}

// ---------------------------------------------------------------------------
// Kernel 1: QKV projection (MFMA) + RoPE epilogue.
// Tile 128(M) x 64(N), 4 waves; wave = 32x64 via 2x4 frags of 16x16x32.
// A = hs [m][k]; B = Wt [n][k] (pre-transposed) -> both frag loads are
// contiguous ds_read_b128. V written transposed [d][s] for the attn kernel.
// ---------------------------------------------------------------------------
__global__ __launch_bounds__(256)
void gemm_qkv(const u16* __restrict__ hs, const u16* __restrict__ wqt,
              const u16* __restrict__ wkt, const u16* __restrict__ wvt,
              const float* __restrict__ ropec, const float* __restrict__ ropes,
              u16* __restrict__ qws, u16* __restrict__ kws, u16* __restrict__ vws)
{
    __shared__ __align__(16) u16 As[128][72];
    __shared__ __align__(16) u16 Bs[64][72];
    const int tid = threadIdx.x;
    const int w = tid >> 6, lane = tid & 63;
    const int l15 = lane & 15, quad = lane >> 4;
    const int row0 = blockIdx.x * 128;
    const int n0   = blockIdx.y * 64;

    const u16* Wt; int nb, mode;
    if (n0 < 2048)      { Wt = wqt; nb = n0;        mode = 0; }
    else if (n0 < 2560) { Wt = wkt; nb = n0 - 2048; mode = 1; }
    else                { Wt = wvt; nb = n0 - 2560; mode = 2; }

    f32x4 acc[2][4];
    #pragma unroll
    for (int mt = 0; mt < 2; ++mt)
        #pragma unroll
        for (int nt = 0; nt < 4; ++nt)
            acc[mt][nt] = (f32x4){0.f, 0.f, 0.f, 0.f};

    for (int k0 = 0; k0 < DMODEL; k0 += 64) {
        __syncthreads();
        #pragma unroll
        for (int it = 0; it < 8; ++it) {
            int e = tid + it * 256;
            int m = e >> 4, k4 = (e & 15) << 2;
            *(ushort4*)&As[m][k4] = *(const ushort4*)(hs + (size_t)(row0 + m) * DMODEL + k0 + k4);
        }
        #pragma unroll
        for (int it = 0; it < 4; ++it) {
            int e = tid + it * 256;
            int nr = e >> 4, k4 = (e & 15) << 2;
            *(ushort4*)&Bs[nr][k4] = *(const ushort4*)(Wt + (size_t)(nb + nr) * DMODEL + k0 + k4);
        }
        __syncthreads();
        #pragma unroll
        for (int ks = 0; ks < 2; ++ks) {
            v8bf a[2], b[4];
            #pragma unroll
            for (int mt = 0; mt < 2; ++mt)
                a[mt] = *(const v8bf*)&As[32*w + 16*mt + l15][ks*32 + quad*8];
            #pragma unroll
            for (int nt = 0; nt < 4; ++nt)
                b[nt] = *(const v8bf*)&Bs[16*nt + l15][ks*32 + quad*8];
            #pragma unroll
            for (int mt = 0; mt < 2; ++mt)
                #pragma unroll
                for (int nt = 0; nt < 4; ++nt)
                    acc[mt][nt] = mfma16(a[mt], b[nt], acc[mt][nt]);
        }
    }

    // Epilogue: C/D layout row = quad*4+reg, col = 16*nt + l15.
    #pragma unroll
    for (int mt = 0; mt < 2; ++mt) {
        #pragma unroll
        for (int nt = 0; nt < 4; ++nt) {
            int col  = n0 + 16*nt + l15;
            int dcol = col & 63;
            #pragma unroll
            for (int reg = 0; reg < 4; ++reg) {
                int row = row0 + 32*w + 16*mt + quad*4 + reg;
                int b = row >> 11, s = row & (SEQ - 1);
                float val = acc[mt][nt][reg];
                if (mode < 2) {   // RoPE (pairs sit in adjacent lanes)
                    float c2 = ropec[(s << 6) + dcol];
                    float s2 = ropes[(s << 6) + dcol];
                    float partner = __shfl_xor(val, 1, 64);
                    val = (dcol & 1) ? (val * c2 + partner * s2)
                                     : (val * c2 - partner * s2);
                }
                if (mode == 0) {
                    int h = col >> 6;
                    qws[((size_t)((b*NH + h) * SEQ + s)) * DH + dcol] = f2bf(val);
                } else if (mode == 1) {
                    int g = (col - 2048) >> 6;
                    kws[((size_t)((b*NG + g) * SEQ + s)) * DH + dcol] = f2bf(val);
                } else {
                    int g = (col - 2560) >> 6;
                    vws[((size_t)((b*NG + g) * DH + dcol)) * SEQ + s] = f2bf(val);
                }
            }
        }
    }
}

// ---------------------------------------------------------------------------
// Kernel 2: flash attention (MFMA). Block = (qtile 64, head, batch), 4 waves;
// wave owns 16 q-rows. QK^T and PV on matrix cores; P round-trips through
// wave-private LDS (C-layout -> A-layout, m120-verified pattern).
// ---------------------------------------------------------------------------
__global__ __launch_bounds__(256)
void attn(const u16* __restrict__ qws, const u16* __restrict__ kws,
          const u16* __restrict__ vws, u16* __restrict__ ctx)
{
    __shared__ __align__(16) u16 Qs[64][72];
    __shared__ __align__(16) u16 Ks[64][72];
    __shared__ __align__(16) u16 Vt[64][72];    // [d][kpos]
    __shared__ __align__(16) u16 Ps[4][16][72]; // wave-private P
    const int tid = threadIdx.x;
    const int w = tid >> 6, lane = tid & 63;
    const int l15 = lane & 15, quad = lane >> 4;
    const int qt = blockIdx.x, h = blockIdx.y, b = blockIdx.z;
    const int g  = h >> 2;
    const int q0 = qt * 64;

    const float slope = exp2f(-0.25f * (float)(h + 1));
    const u16* qbase  = qws + (size_t)(b*NH + h) * SEQ * DH;
    const u16* kbase  = kws + (size_t)(b*NG + g) * SEQ * DH;
    const u16* vtbase = vws + (size_t)(b*NG + g) * DH * SEQ;   // [d][s]

    #pragma unroll
    for (int it = 0; it < 4; ++it) {
        int e = tid + it * 256;
        int m = e >> 4, d4 = (e & 15) << 2;
        *(ushort4*)&Qs[m][d4] = *(const ushort4*)(qbase + (size_t)(q0 + m) * DH + d4);
    }

    f32x4 o[4];
    #pragma unroll
    for (int dt = 0; dt < 4; ++dt) o[dt] = (f32x4){0.f, 0.f, 0.f, 0.f};
    float mrow[4] = {NEG_BIG, NEG_BIG, NEG_BIG, NEG_BIG};
    float lrow[4] = {0.f, 0.f, 0.f, 0.f};

    for (int kt = 0; kt <= qt; ++kt) {
        const int k0 = kt * 64;
        __syncthreads();   // prior PV reads of Ks/Vt done (also covers Qs on iter 0)
        #pragma unroll
        for (int it = 0; it < 4; ++it) {
            int e = tid + it * 256;
            int r = e >> 4, c4 = (e & 15) << 2;
            *(ushort4*)&Ks[r][c4] = *(const ushort4*)(kbase + (size_t)(k0 + r) * DH + c4);
            *(ushort4*)&Vt[r][c4] = *(const ushort4*)(vtbase + (size_t)r * SEQ + k0 + c4);
        }
        __syncthreads();

        f32x4 sacc[4];
        #pragma unroll
        for (int nt = 0; nt < 4; ++nt) sacc[nt] = (f32x4){0.f, 0.f, 0.f, 0.f};
        #pragma unroll
        for (int ks = 0; ks < 2; ++ks) {
            v8bf a = *(const v8bf*)&Qs[16*w + l15][ks*32 + quad*8];
            #pragma unroll
            for (int nt = 0; nt < 4; ++nt) {
                v8bf bb = *(const v8bf*)&Ks[16*nt + l15][ks*32 + quad*8];
                sacc[nt] = mfma16(a, bb, sacc[nt]);
            }
        }

        // alibi + scale + 30*tanh(x/30) + causal (diag tile only)
        const bool diag = (kt == qt);
        #pragma unroll
        for (int nt = 0; nt < 4; ++nt) {
            int kpos = k0 + 16*nt + l15;
            #pragma unroll
            for (int reg = 0; reg < 4; ++reg) {
                int qpos = q0 + 16*w + quad*4 + reg;
                float sv = (sacc[nt][reg] - fabsf((float)(qpos - kpos)) * slope) * 0.125f;
                float x = sv * (1.0f / 30.0f);
                float ax = fabsf(x);
                float t = __expf(-2.0f * ax);
                float th = (1.0f - t) / (1.0f + t);
                sv = 30.0f * ((x >= 0.f) ? th : -th);
                if (diag && kpos > qpos) sv = NEG_BIG;
                sacc[nt][reg] = sv;
            }
        }

        // online softmax; row state replicated across the 16-lane quad group
        #pragma unroll
        for (int reg = 0; reg < 4; ++reg) {
            float mx = fmaxf(fmaxf(sacc[0][reg], sacc[1][reg]),
                             fmaxf(sacc[2][reg], sacc[3][reg]));
            #pragma unroll
            for (int off = 1; off < 16; off <<= 1)
                mx = fmaxf(mx, __shfl_xor(mx, off, 64));
            float mnew = fmaxf(mrow[reg], mx);
            float alpha = __expf(mrow[reg] - mnew);
            float psum = 0.f;
            #pragma unroll
            for (int nt = 0; nt < 4; ++nt) {
                float p = __expf(sacc[nt][reg] - mnew);
                sacc[nt][reg] = p;
                psum += p;
            }
            #pragma unroll
            for (int off = 1; off < 16; off <<= 1)
                psum += __shfl_xor(psum, off, 64);
            lrow[reg] = lrow[reg] * alpha + psum;
            mrow[reg] = mnew;
            #pragma unroll
            for (int dt = 0; dt < 4; ++dt) o[dt][reg] *= alpha;
        }

        // P: C-layout -> wave-private LDS -> A-layout
        #pragma unroll
        for (int nt = 0; nt < 4; ++nt)
            #pragma unroll
            for (int reg = 0; reg < 4; ++reg)
                Ps[w][quad*4 + reg][16*nt + l15] = f2bf(sacc[nt][reg]);

        #pragma unroll
        for (int ks = 0; ks < 2; ++ks) {
            v8bf pa = *(const v8bf*)&Ps[w][l15][ks*32 + quad*8];
            #pragma unroll
            for (int dt = 0; dt < 4; ++dt) {
                v8bf vb = *(const v8bf*)&Vt[16*dt + l15][ks*32 + quad*8];
                o[dt] = mfma16(pa, vb, o[dt]);
            }
        }
    }

    #pragma unroll
    for (int reg = 0; reg < 4; ++reg) {
        int s = q0 + 16*w + quad*4 + reg;
        float inv = 1.0f / lrow[reg];
        #pragma unroll
        for (int dt = 0; dt < 4; ++dt)
            ctx[((size_t)(b*SEQ + s) * NH + h) * DH + 16*dt + l15] = f2bf(o[dt][reg] * inv);
    }
}

// ---------------------------------------------------------------------------
// Kernel 3: out = ctx @ Wo + bo (MFMA). Dual-dtype store per detected flavor.
// ---------------------------------------------------------------------------
__global__ __launch_bounds__(256)
void oproj(const u16* __restrict__ ctx, const u16* __restrict__ wot,
           const u16* __restrict__ bo, const u16* __restrict__ hs_orig,
           void* __restrict__ outp)
{
    __shared__ float red[4];
    __shared__ __align__(16) u16 As[128][72];
    __shared__ __align__(16) u16 Bs[64][72];
    const int tid = threadIdx.x;
    const bool is_f32 = detect_is_f32(hs_orig, tid, red);
    const int w = tid >> 6, lane = tid & 63;
    const int l15 = lane & 15, quad = lane >> 4;
    const int row0 = blockIdx.x * 128;
    const int n0   = blockIdx.y * 64;

    f32x4 acc[2][4];
    #pragma unroll
    for (int mt = 0; mt < 2; ++mt)
        #pragma unroll
        for (int nt = 0; nt < 4; ++nt)
            acc[mt][nt] = (f32x4){0.f, 0.f, 0.f, 0.f};

    for (int k0 = 0; k0 < DMODEL; k0 += 64) {
        __syncthreads();
        #pragma unroll
        for (int it = 0; it < 8; ++it) {
            int e = tid + it * 256;
            int m = e >> 4, k4 = (e & 15) << 2;
            *(ushort4*)&As[m][k4] = *(const ushort4*)(ctx + (size_t)(row0 + m) * DMODEL + k0 + k4);
        }
        #pragma unroll
        for (int it = 0; it < 4; ++it) {
            int e = tid + it * 256;
            int nr = e >> 4, k4 = (e & 15) << 2;
            *(ushort4*)&Bs[nr][k4] = *(const ushort4*)(wot + (size_t)(n0 + nr) * DMODEL + k0 + k4);
        }
        __syncthreads();
        #pragma unroll
        for (int ks = 0; ks < 2; ++ks) {
            v8bf a[2], b[4];
            #pragma unroll
            for (int mt = 0; mt < 2; ++mt)
                a[mt] = *(const v8bf*)&As[32*w + 16*mt + l15][ks*32 + quad*8];
            #pragma unroll
            for (int nt = 0; nt < 4; ++nt)
                b[nt] = *(const v8bf*)&Bs[16*nt + l15][ks*32 + quad*8];
            #pragma unroll
            for (int mt = 0; mt < 2; ++mt)
                #pragma unroll
                for (int nt = 0; nt < 4; ++nt)
                    acc[mt][nt] = mfma16(a[mt], b[nt], acc[mt][nt]);
        }
    }

    #pragma unroll
    for (int mt = 0; mt < 2; ++mt) {
        #pragma unroll
        for (int nt = 0; nt < 4; ++nt) {
            int col = n0 + 16*nt + l15;
            float bias = bf2f(bo[col]);
            #pragma unroll
            for (int reg = 0; reg < 4; ++reg) {
                int row = row0 + 32*w + 16*mt + quad*4 + reg;
                float val = acc[mt][nt][reg] + bias;
                if (is_f32) ((float*)outp)[(size_t)row * DMODEL + col] = val;
                else        ((u16*)outp)[(size_t)row * DMODEL + col]   = f2bf(val);
            }
        }
    }
}

extern "C" void kernel_launch(void* const* d_in, const int* in_sizes, int n_in,
                              void* d_out, int out_size, void* d_ws, size_t ws_size,
                              hipStream_t stream) {
    u16* ws = (u16*)d_ws;
    u16* canon = ws;
    u16* qws = ws + W_Q;
    u16* kws = ws + W_K;
    u16* vws = ws + W_V;
    u16* ctxp = ws + W_CTX;
    float* ropec = (float*)(ws + W_CTX);          // transient, overwritten by ctx later
    float* ropes = ropec + SEQ * DH;
    const u16* hs_raw = (const u16*)d_in[0];

    conv_hs_bo<<<dim3(4097), 256, 0, stream>>>(d_in[0], d_in[5], canon);
    transp_w<<<dim3(32, 32), 256, 0, stream>>>(d_in[1], canon + C_WQ, 2048, 2048, hs_raw);
    transp_w<<<dim3(8, 32),  256, 0, stream>>>(d_in[2], canon + C_WK, 2048, 512, hs_raw);
    transp_w<<<dim3(8, 32),  256, 0, stream>>>(d_in[3], canon + C_WV, 2048, 512, hs_raw);
    transp_w<<<dim3(32, 32), 256, 0, stream>>>(d_in[4], canon + C_WO, 2048, 2048, hs_raw);
    rope_table<<<dim3(512), 256, 0, stream>>>(ropec, ropes);
    gemm_qkv<<<dim3(32, 48), 256, 0, stream>>>(canon + C_HS, canon + C_WQ,
        canon + C_WK, canon + C_WV, ropec, ropes, qws, kws, vws);
    attn<<<dim3(SEQ/64, NH, 2), 256, 0, stream>>>(qws, kws, vws, ctxp);
    oproj<<<dim3(32, 32), 256, 0, stream>>>(ctxp, canon + C_WO, canon + C_BO,
        hs_raw, d_out);
}